// Round 12
// baseline (388.655 us; speedup 1.0000x reference)
//
#include <hip/hip_runtime.h>
#include <hip/hip_fp16.h>

#define NN 100000
#define EE 3200000
#define NB 256          // dst-range buckets
#define NPB 391         // nodes per bucket = ceil(NN/NB)
#define BCAP 13568      // per-bucket staging capacity (mean 12500, +9.5 sigma)
#define NBLK_A 512      // passA2 blocks
#define CHUNK_A (EE / NBLK_A)   // 6250 edges per block

// workspace layout (bytes)
#define OFF_AF   0UL            // half[NN*64] 12.8MB true-h2  (gbuf 12.8MB overlays at start)
#define OFF_AH   25600000UL     // half[NN*64] 12.8MB h1' (gemm1 out)
#define OFF_BH   38400000UL     // half[NN*64] 12.8MB (wf 64KB + cnt/loc/P overlays early; Uh later)
#define OFF_CNT  (OFF_BH + 65536UL)           // int[512*256] 512KB
#define OFF_LOC  (OFF_CNT + 524288UL)         // int[512*256] 512KB
#define OFF_P    (OFF_LOC + 524288UL)         // int[512*256] 512KB
#define OFF_CSR  51200000UL     // int[EE]     12.8MB
#define OFF_RP   64000000UL     // int[NN+1]
#define OFF_DINV 64400384UL     // float[NN]
#define OFF_SEG  64800768UL     // int[256]  (bucket totals)
#define OFF_BASE 64808960UL     // int[257]
#define OFF_BN   64813056UL     // float[128]
#define OFF_SS   64813568UL     // float[128]
// total ~64.8 MB

typedef __attribute__((ext_vector_type(8))) short bf16x8;
typedef __attribute__((ext_vector_type(4))) float f32x4;

// ---- CSR build, stage 1: per-block LDS bucket sort + coalesced dump ----
__global__ __launch_bounds__(256) void passA2(const int* __restrict__ src, const int* __restrict__ dst,
                                              int* __restrict__ cnt, int* __restrict__ loc,
                                              unsigned* __restrict__ gbuf) {
    __shared__ unsigned ebuf[CHUNK_A];
    __shared__ int hist[NB], cur[NB], sc[NB];
    int t = threadIdx.x, b = blockIdx.x;
    hist[t] = 0;
    __syncthreads();
    int beg = b * CHUNK_A;
    for (int i = t; i < CHUNK_A; i += 256)
        atomicAdd(&hist[dst[beg + i] / NPB], 1);
    __syncthreads();
    int h = hist[t];
    sc[t] = h;
    __syncthreads();
    for (int off = 1; off < 256; off <<= 1) {
        int v = (t >= off) ? sc[t - off] : 0;
        __syncthreads();
        sc[t] += v;
        __syncthreads();
    }
    int ex = sc[t] - h;            // exclusive prefix = local bucket start
    cur[t] = ex;
    loc[b * NB + t] = ex;
    cnt[b * NB + t] = h;
    __syncthreads();
    for (int i = t; i < CHUNK_A; i += 256) {
        int d = dst[beg + i];
        int k = d / NPB;
        int dl = d - k * NPB;
        int p = atomicAdd(&cur[k], 1);   // p < CHUNK_A by construction
        ebuf[p] = ((unsigned)dl << 17) | (unsigned)src[beg + i];
    }
    __syncthreads();
    for (int i = t; i < CHUNK_A; i += 256)
        gbuf[beg + i] = ebuf[i];         // fully coalesced dump
}

// stage 2: per-bucket column prefix over blocks + totals
__global__ __launch_bounds__(512) void colscan(const int* __restrict__ cnt, int* __restrict__ P,
                                               int* __restrict__ total) {
    __shared__ int s[512];
    int k = blockIdx.x, t = threadIdx.x;
    int v = cnt[t * NB + k];
    s[t] = v;
    __syncthreads();
    for (int off = 1; off < 512; off <<= 1) {
        int u = (t >= off) ? s[t - off] : 0;
        __syncthreads();
        s[t] += u;
        __syncthreads();
    }
    P[t * NB + k] = s[t] - v;
    if (t == 511) total[k] = s[511];
}

// stage 3: bucket bases
__global__ __launch_bounds__(256) void basescan(const int* __restrict__ total, int* __restrict__ base,
                                                int* __restrict__ rp) {
    __shared__ int s[256];
    int t = threadIdx.x;
    int v = total[t];
    s[t] = v;
    __syncthreads();
    for (int off = 1; off < 256; off <<= 1) {
        int u = (t >= off) ? s[t - off] : 0;
        __syncthreads();
        s[t] += u;
        __syncthreads();
    }
    base[t] = s[t] - v;
    if (t == 255) { base[256] = s[255]; rp[NN] = s[255]; }
}

// stage 4: per-bucket gather of runs (contiguous reads), deg, scan, rp/dinv, csr
__global__ __launch_bounds__(512) void passB2(const unsigned* __restrict__ gbuf,
                                              const int* __restrict__ cnt, const int* __restrict__ loc,
                                              const int* __restrict__ P, const int* __restrict__ total,
                                              const int* __restrict__ base,
                                              int* __restrict__ rp, float* __restrict__ dinv,
                                              int* __restrict__ csr) {
    __shared__ unsigned ebuf[BCAP];
    __shared__ int deg_l[NPB];
    __shared__ int off_l[NPB];
    __shared__ int s[512];
    int k = blockIdx.x, t = threadIdx.x;
    int nb = min(total[k], BCAP);
    for (int i = t; i < NPB; i += 512) deg_l[i] = 0;
    int wid = t >> 6, lane = t & 63;
    for (int b = wid; b < NBLK_A; b += 8) {
        int n = cnt[b * NB + k];
        int so = b * CHUNK_A + loc[b * NB + k];
        int dofs = P[b * NB + k];
        for (int e = lane; e < n; e += 64)
            if (dofs + e < BCAP) ebuf[dofs + e] = gbuf[so + e];
    }
    __syncthreads();
    for (int j = t; j < nb; j += 512) atomicAdd(&deg_l[ebuf[j] >> 17], 1);
    __syncthreads();
    int d0 = (t < NPB) ? deg_l[t] : 0;
    s[t] = d0;
    __syncthreads();
    for (int off = 1; off < 512; off <<= 1) {
        int v = (t >= off) ? s[t - off] : 0;
        __syncthreads();
        s[t] += v;
        __syncthreads();
    }
    if (t < NPB) off_l[t] = s[t] - d0;
    __syncthreads();
    int nodebase = k * NPB;
    int cbase = base[k];
    for (int i = t; i < NPB; i += 512) {
        int node = nodebase + i;
        if (node < NN) {
            rp[node] = cbase + off_l[i];
            dinv[node] = rsqrtf((float)deg_l[i] + 1.0f);
        }
    }
    __syncthreads();
    for (int j = t; j < nb; j += 512) {
        unsigned e = ebuf[j];
        int p = atomicAdd(&off_l[e >> 17], 1);
        csr[cbase + p] = (int)(e & 0x1FFFFu);
    }
}

// W1 -> MFMA B-fragment layout, bf16 hi/lo: wf[ks][nt][h][lane][8]
__global__ __launch_bounds__(256) void wprep(const float* __restrict__ W1, short* __restrict__ wf) {
    int e = blockIdx.x * 256 + threadIdx.x;   // 16384 elements
    if (e >= 16384) return;
    int j = e & 7, lane = (e >> 3) & 63, nt = (e >> 9) & 3, ks = e >> 11;
    int k = ks * 32 + (lane >> 4) * 8 + j;
    int col = nt * 16 + (lane & 15);
    float w = W1[k * 64 + col];
    unsigned b = __float_as_uint(w);
    short hi = (short)(b >> 16);
    float hf = __uint_as_float(b & 0xFFFF0000u);
    float lo = w - hf;
    short lov = (short)(__float_as_uint(lo) >> 16);
    wf[((size_t)(ks * 8 + nt * 2 + 0) * 64 + lane) * 8 + j] = hi;
    wf[((size_t)(ks * 8 + nt * 2 + 1) * 64 + lane) * 8 + j] = lov;
}

// A_h[N,64] = half( dinv[i] * (x @ W1) ) via LDS-free split-bf16 MFMA.
__global__ __launch_bounds__(256) void gemm1(const float* __restrict__ x, const short* __restrict__ wf,
                                             const float* __restrict__ dinv, __half* __restrict__ Ah) {
    int wid = threadIdx.x >> 6, lane = threadIdx.x & 63;
    int g = blockIdx.x * 4 + wid;        // 16-row group per wave
    if (g >= NN / 16) return;            // 6250 groups (exact)
    int lrow = g * 16 + (lane & 15);
    int kgrp = (lane >> 4) * 8;
    const float* xp = x + (size_t)lrow * 256 + kgrp;
    f32x4 acc[4];
    #pragma unroll
    for (int nt = 0; nt < 4; ++nt) acc[nt] = (f32x4){0.f, 0.f, 0.f, 0.f};
    for (int ks = 0; ks < 8; ++ks) {
        float4 f0 = *(const float4*)(xp + ks * 32);
        float4 f1 = *(const float4*)(xp + ks * 32 + 4);
        bf16x8 a_hi, a_lo;
        const float* fp = &f0.x;
        #pragma unroll
        for (int j = 0; j < 8; ++j) {
            float f = (j < 4) ? fp[j] : (&f1.x)[j - 4];
            unsigned b = __float_as_uint(f);
            a_hi[j] = (short)(b >> 16);
            float lo = f - __uint_as_float(b & 0xFFFF0000u);
            a_lo[j] = (short)(__float_as_uint(lo) >> 16);
        }
        const short* wfk = wf + (size_t)(ks * 8) * 64 * 8;
        #pragma unroll
        for (int nt = 0; nt < 4; ++nt) {
            bf16x8 b_hi = *(const bf16x8*)(wfk + ((nt * 2 + 0) * 64 + lane) * 8);
            bf16x8 b_lo = *(const bf16x8*)(wfk + ((nt * 2 + 1) * 64 + lane) * 8);
            acc[nt] = __builtin_amdgcn_mfma_f32_16x16x32_bf16(a_hi, b_hi, acc[nt], 0, 0, 0);
            acc[nt] = __builtin_amdgcn_mfma_f32_16x16x32_bf16(a_hi, b_lo, acc[nt], 0, 0, 0);
            acc[nt] = __builtin_amdgcn_mfma_f32_16x16x32_bf16(a_lo, b_hi, acc[nt], 0, 0, 0);
        }
    }
    int mb = (lane >> 4) * 4;
    #pragma unroll
    for (int reg = 0; reg < 4; ++reg) {
        int row = g * 16 + mb + reg;
        float dv = dinv[row];
        #pragma unroll
        for (int nt = 0; nt < 4; ++nt)
            Ah[(size_t)row * 64 + nt * 16 + (lane & 15)] = __float2half(acc[nt][reg] * dv);
    }
}

// fp16 gather aggregation on 64 ch: lane = channel pair (half2), wave halves
// process 2 edges simultaneously; 16-deep unroll keeps 8 gathers in flight.
template <int P>
__global__ __launch_bounds__(256) void agg64h(const __half* __restrict__ h, __half* __restrict__ outp,
                                              const int* __restrict__ rp, const int* __restrict__ csr,
                                              const float* __restrict__ dinv) {
    int lane = threadIdx.x & 63;
    int node = (blockIdx.x << 2) + (threadIdx.x >> 6);
    if (node >= NN) return;
    int hid = lane >> 5;            // which edge of the pair
    int c2 = (lane & 31) * 2;       // channel pair base
    float dd = dinv[node];
    float ax = 0.f, ay = 0.f, bx = 0.f, by = 0.f;
    if (hid == 0) {
        __half2 sv = *(const __half2*)(h + (size_t)node * 64 + c2);
        ax = __half2float(sv.x); ay = __half2float(sv.y);
    }
    int beg = rp[node], end = rp[node + 1];
    for (int j0 = beg; j0 < end; j0 += 64) {
        int m = end - j0; if (m > 64) m = 64;
        int s = csr[j0 + (lane < m ? lane : 0)];
        int j = 0;
        for (; j + 15 < m; j += 16) {
            int i0 = __shfl(s, j + hid);
            int i1 = __shfl(s, j + 2 + hid);
            int i2 = __shfl(s, j + 4 + hid);
            int i3 = __shfl(s, j + 6 + hid);
            int i4 = __shfl(s, j + 8 + hid);
            int i5 = __shfl(s, j + 10 + hid);
            int i6 = __shfl(s, j + 12 + hid);
            int i7 = __shfl(s, j + 14 + hid);
            __half2 v0 = *(const __half2*)(h + (size_t)i0 * 64 + c2);
            __half2 v1 = *(const __half2*)(h + (size_t)i1 * 64 + c2);
            __half2 v2 = *(const __half2*)(h + (size_t)i2 * 64 + c2);
            __half2 v3 = *(const __half2*)(h + (size_t)i3 * 64 + c2);
            __half2 v4 = *(const __half2*)(h + (size_t)i4 * 64 + c2);
            __half2 v5 = *(const __half2*)(h + (size_t)i5 * 64 + c2);
            __half2 v6 = *(const __half2*)(h + (size_t)i6 * 64 + c2);
            __half2 v7 = *(const __half2*)(h + (size_t)i7 * 64 + c2);
            ax += __half2float(v0.x) + __half2float(v2.x);
            ay += __half2float(v0.y) + __half2float(v2.y);
            bx += __half2float(v1.x) + __half2float(v3.x);
            by += __half2float(v1.y) + __half2float(v3.y);
            ax += __half2float(v4.x) + __half2float(v6.x);
            ay += __half2float(v4.y) + __half2float(v6.y);
            bx += __half2float(v5.x) + __half2float(v7.x);
            by += __half2float(v5.y) + __half2float(v7.y);
        }
        for (; j + 7 < m; j += 8) {
            int i0 = __shfl(s, j + hid);
            int i1 = __shfl(s, j + 2 + hid);
            int i2 = __shfl(s, j + 4 + hid);
            int i3 = __shfl(s, j + 6 + hid);
            __half2 v0 = *(const __half2*)(h + (size_t)i0 * 64 + c2);
            __half2 v1 = *(const __half2*)(h + (size_t)i1 * 64 + c2);
            __half2 v2 = *(const __half2*)(h + (size_t)i2 * 64 + c2);
            __half2 v3 = *(const __half2*)(h + (size_t)i3 * 64 + c2);
            ax += __half2float(v0.x) + __half2float(v2.x);
            ay += __half2float(v0.y) + __half2float(v2.y);
            bx += __half2float(v1.x) + __half2float(v3.x);
            by += __half2float(v1.y) + __half2float(v3.y);
        }
        for (; j < m; j += 2) {
            int idx = j + hid;
            int cidx = idx < m ? idx : m - 1;
            int sj = __shfl(s, cidx);
            if (idx < m) {
                __half2 v = *(const __half2*)(h + (size_t)sj * 64 + c2);
                ax += __half2float(v.x); ay += __half2float(v.y);
            }
        }
    }
    float sx = ax + bx, sy = ay + by;
    sx += __shfl(sx, lane ^ 32);
    sy += __shfl(sy, lane ^ 32);
    if (hid == 0) {
        float w = (P == 2) ? dd * dd : dd;
        __half2 o;
        o.x = __float2half(sx * w); o.y = __float2half(sy * w);
        *(__half2*)(outp + (size_t)node * 64 + c2) = o;
    }
}

// fp16 gather on 32 ch, 4 edges per wave-iter, fused +b2 and log_softmax.
__global__ __launch_bounds__(256) void agg32f(const __half* __restrict__ U, float* __restrict__ outp,
                                              const int* __restrict__ rp, const int* __restrict__ csr,
                                              const float* __restrict__ dinv, const float* __restrict__ b2) {
    int lane = threadIdx.x & 63;
    int node = (blockIdx.x << 2) + (threadIdx.x >> 6);
    if (node >= NN) return;
    int gid = lane >> 4;            // which edge of the quad
    int c2 = (lane & 15) * 2;       // channel pair base
    float dd = dinv[node];
    float ax = 0.f, ay = 0.f;
    if (gid == 0) {
        __half2 sv = *(const __half2*)(U + (size_t)node * 32 + c2);
        ax = __half2float(sv.x); ay = __half2float(sv.y);
    }
    int beg = rp[node], end = rp[node + 1];
    for (int j0 = beg; j0 < end; j0 += 64) {
        int m = end - j0; if (m > 64) m = 64;
        int s = csr[j0 + (lane < m ? lane : 0)];
        int j = 0;
        for (; j + 15 < m; j += 16) {
            int i0 = __shfl(s, j + gid);
            int i1 = __shfl(s, j + 4 + gid);
            int i2 = __shfl(s, j + 8 + gid);
            int i3 = __shfl(s, j + 12 + gid);
            __half2 v0 = *(const __half2*)(U + (size_t)i0 * 32 + c2);
            __half2 v1 = *(const __half2*)(U + (size_t)i1 * 32 + c2);
            __half2 v2 = *(const __half2*)(U + (size_t)i2 * 32 + c2);
            __half2 v3 = *(const __half2*)(U + (size_t)i3 * 32 + c2);
            ax += __half2float(v0.x) + __half2float(v1.x) + __half2float(v2.x) + __half2float(v3.x);
            ay += __half2float(v0.y) + __half2float(v1.y) + __half2float(v2.y) + __half2float(v3.y);
        }
        for (; j + 7 < m; j += 8) {
            int i0 = __shfl(s, j + gid);
            int i1 = __shfl(s, j + 4 + gid);
            __half2 v0 = *(const __half2*)(U + (size_t)i0 * 32 + c2);
            __half2 v1 = *(const __half2*)(U + (size_t)i1 * 32 + c2);
            ax += __half2float(v0.x) + __half2float(v1.x);
            ay += __half2float(v0.y) + __half2float(v1.y);
        }
        for (; j < m; j += 4) {
            int idx = j + gid;
            int cidx = idx < m ? idx : m - 1;
            int sj = __shfl(s, cidx);
            if (idx < m) {
                __half2 v = *(const __half2*)(U + (size_t)sj * 32 + c2);
                ax += __half2float(v.x); ay += __half2float(v.y);
            }
        }
    }
    ax += __shfl(ax, lane ^ 16); ay += __shfl(ay, lane ^ 16);
    ax += __shfl(ax, lane ^ 32); ay += __shfl(ay, lane ^ 32);
    float v0 = ax * dd + b2[c2];
    float v1 = ay * dd + b2[c2 + 1];
    float mx = fmaxf(v0, v1);
    mx = fmaxf(mx, __shfl_xor(mx, 1));
    mx = fmaxf(mx, __shfl_xor(mx, 2));
    mx = fmaxf(mx, __shfl_xor(mx, 4));
    mx = fmaxf(mx, __shfl_xor(mx, 8));
    float sum = __expf(v0 - mx) + __expf(v1 - mx);
    sum += __shfl_xor(sum, 1);
    sum += __shfl_xor(sum, 2);
    sum += __shfl_xor(sum, 4);
    sum += __shfl_xor(sum, 8);
    if (gid == 0) {
        float ls = __logf(sum);
        *(float2*)(outp + (size_t)node * 32 + c2) = make_float2(v0 - mx - ls, v1 - mx - ls);
    }
}

__global__ __launch_bounds__(256) void bn_stats(const __half* __restrict__ A, float* __restrict__ bn) {
    int t = threadIdx.x;
    int c = t & 63, rg = t >> 6;
    float s = 0.f, sq = 0.f;
    for (int r = blockIdx.x * 4 + rg; r < NN; r += gridDim.x * 4) {
        float v = __half2float(A[(size_t)r * 64 + c]);
        s += v; sq += v * v;
    }
    __shared__ float ls[256], lq[256];
    ls[t] = s; lq[t] = sq;
    __syncthreads();
    if (t < 64) {
        float S = ls[t] + ls[t + 64] + ls[t + 128] + ls[t + 192];
        float Q = lq[t] + lq[t + 64] + lq[t + 128] + lq[t + 192];
        atomicAdd(&bn[t], S);
        atomicAdd(&bn[64 + t], Q);
    }
}

__global__ void bn_final(const float* __restrict__ bn, const float* __restrict__ gamma,
                         const float* __restrict__ beta, float* __restrict__ ss) {
    int c = threadIdx.x;   // 64 threads
    float mean = bn[c] / (float)NN;
    float var = bn[64 + c] / (float)NN - mean * mean;
    float sc = gamma[c] * rsqrtf(var + 1e-5f);
    ss[c] = sc;
    ss[64 + c] = beta[c] - mean * sc;
}

// U_h[N,32] = half( dinv[i] * (selu(bn(A[N,64])) @ W2[64,32]) )
__global__ __launch_bounds__(256) void gemm2(const __half* __restrict__ A, const float* __restrict__ W2,
                                             const float* __restrict__ ss, const float* __restrict__ dinv,
                                             __half* __restrict__ U) {
    __shared__ float w2s[64 * 32];
    __shared__ float sc[64], sh[64];
    for (int i = threadIdx.x; i < 512; i += 256)
        ((float4*)w2s)[i] = ((const float4*)W2)[i];
    if (threadIdx.x < 64) {
        sc[threadIdx.x] = ss[threadIdx.x];
        sh[threadIdx.x] = ss[64 + threadIdx.x];
    }
    __syncthreads();
    const float SELU_S = 1.0507009873554805f;
    const float SELU_AS = 1.7580993408473766f;   // scale*alpha
    int lane = threadIdx.x & 31, grp = threadIdx.x >> 5;
    int node = blockIdx.x * 8 + grp;
    if (node >= NN) return;
    const __half* Ar = A + (size_t)node * 64;
    float v0 = __half2float(Ar[lane]);
    float v1 = __half2float(Ar[lane + 32]);
    v0 = v0 * sc[lane] + sh[lane];
    v1 = v1 * sc[lane + 32] + sh[lane + 32];
    v0 = v0 > 0.f ? SELU_S * v0 : SELU_AS * (__expf(v0) - 1.0f);
    v1 = v1 > 0.f ? SELU_S * v1 : SELU_AS * (__expf(v1) - 1.0f);
    float acc = 0.f;
    #pragma unroll
    for (int j = 0; j < 32; ++j) {
        acc += __shfl(v0, j, 32) * w2s[j * 32 + lane];
        acc += __shfl(v1, j, 32) * w2s[(j + 32) * 32 + lane];
    }
    U[(size_t)node * 32 + lane] = __float2half(dinv[node] * acc);
}

extern "C" void kernel_launch(void* const* d_in, const int* in_sizes, int n_in,
                              void* d_out, int out_size, void* d_ws, size_t ws_size,
                              hipStream_t stream) {
    const float* x     = (const float*)d_in[0];
    const int*   src   = (const int*)d_in[1];
    const int*   dst   = (const int*)d_in[2];
    const float* W1    = (const float*)d_in[3];
    // d_in[4] = b1 : cancels inside BatchNorm, unused
    const float* gamma = (const float*)d_in[5];
    const float* beta  = (const float*)d_in[6];
    const float* W2    = (const float*)d_in[7];
    const float* b2    = (const float*)d_in[8];
    float* out = (float*)d_out;

    char* ws = (char*)d_ws;
    __half*   Af   = (__half*)(ws + OFF_AF);    // true h2, fp16
    unsigned* gbuf = (unsigned*)(ws + OFF_AF);  // 12.8MB overlay, consumed by passB2
    __half*   Ah   = (__half*)(ws + OFF_AH);
    __half*   Bh   = (__half*)(ws + OFF_BH);
    short*    wf   = (short*)(ws + OFF_BH);     // 64KB overlay, consumed by gemm1
    __half*   Uh   = (__half*)(ws + OFF_BH);    // 6.4MB overlay, written after Bh consumed
    int*      cnt  = (int*)(ws + OFF_CNT);      // overlays BH+64KB, consumed pre-agg
    int*      loc  = (int*)(ws + OFF_LOC);
    int*      Pm   = (int*)(ws + OFF_P);
    int*      csr  = (int*)(ws + OFF_CSR);
    int*      rp   = (int*)(ws + OFF_RP);
    float*    dinv = (float*)(ws + OFF_DINV);
    int*      tot  = (int*)(ws + OFF_SEG);
    int*      base = (int*)(ws + OFF_BASE);
    float*    bn   = (float*)(ws + OFF_BN);
    float*    ssb  = (float*)(ws + OFF_SS);

    hipMemsetAsync(bn, 0, 128 * sizeof(float), stream);

    // W1 -> bf16 hi/lo MFMA fragments (parked in BH head, consumed by gemm1)
    wprep<<<64, 256, 0, stream>>>(W1, wf);

    // CSR build: LDS bucket-sort + coalesced dump, scans, per-bucket finish
    passA2<<<NBLK_A, 256, 0, stream>>>(src, dst, cnt, loc, gbuf);
    colscan<<<NB, 512, 0, stream>>>(cnt, Pm, tot);
    basescan<<<1, 256, 0, stream>>>(tot, base, rp);
    passB2<<<NB, 512, 0, stream>>>(gbuf, cnt, loc, Pm, tot, base, rp, dinv, csr);

    // conv1: Ah = half(dinv*(x@W1)) via LDS-free split-bf16 MFMA, then two fp16 propagations
    gemm1<<<(NN / 16 + 3) / 4, 256, 0, stream>>>(x, wf, dinv, Ah);
    agg64h<2><<<NN / 4, 256, 0, stream>>>(Ah, Bh, rp, csr, dinv);  // Bh pre-scaled
    agg64h<1><<<NN / 4, 256, 0, stream>>>(Bh, Af, rp, csr, dinv);  // Af = true h2 (fp16)

    // batchnorm stats (b1 cancels), fold gamma/beta into scale/shift
    bn_stats<<<1024, 256, 0, stream>>>(Af, bn);
    bn_final<<<1, 64, 0, stream>>>(bn, gamma, beta, ssb);

    // conv2: Uh = half(dinv*(selu(bn(Af)) @ W2)), then fp16 propagate + fused log_softmax
    gemm2<<<NN / 8, 256, 0, stream>>>(Af, W2, ssb, dinv, Uh);
    agg32f<<<NN / 4, 256, 0, stream>>>(Uh, out, rp, csr, dinv, b2);
}

// Round 13
// 354.520 us; speedup vs baseline: 1.0963x; 1.0963x over previous
//
#include <hip/hip_runtime.h>
#include <hip/hip_fp16.h>

#define NN 100000
#define EE 3200000
#define NB 256          // dst-range buckets
#define NPB 391         // nodes per bucket = ceil(NN/NB)
#define NBLK_A 512      // passA2 blocks (= runs per bucket)
#define CHUNK_A (EE / NBLK_A)   // 6250 edges per block

// workspace layout (bytes)
#define OFF_AF   0UL            // half[NN*64] 12.8MB true-h2  (gbuf 12.8MB overlays at start)
#define OFF_AH   25600000UL     // half[NN*64] 12.8MB h1' (gemm1 out)
#define OFF_BH   38400000UL     // half[NN*64] 12.8MB (wf 64KB + cnt/loc overlays early; Uh later)
#define OFF_CNT  (OFF_BH + 65536UL)           // int[512*256] 512KB
#define OFF_LOC  (OFF_CNT + 524288UL)         // int[512*256] 512KB
#define OFF_CSR  51200000UL     // int[EE]     12.8MB
#define OFF_RP   64000000UL     // int[NN+1]
#define OFF_DINV 64400384UL     // float[NN]
#define OFF_BASE 64808960UL     // int[257]
#define OFF_BN   64813056UL     // float[128]
#define OFF_SS   64813568UL     // float[128]
// total ~64.8 MB

typedef __attribute__((ext_vector_type(8))) short bf16x8;
typedef __attribute__((ext_vector_type(4))) float f32x4;

// ---- CSR build, stage 1: per-block LDS bucket sort + coalesced dump ----
__global__ __launch_bounds__(256) void passA2(const int* __restrict__ src, const int* __restrict__ dst,
                                              int* __restrict__ cnt, int* __restrict__ loc,
                                              unsigned* __restrict__ gbuf) {
    __shared__ unsigned ebuf[CHUNK_A];
    __shared__ int hist[NB], cur[NB], sc[NB];
    int t = threadIdx.x, b = blockIdx.x;
    hist[t] = 0;
    __syncthreads();
    int beg = b * CHUNK_A;
    for (int i = t; i < CHUNK_A; i += 256)
        atomicAdd(&hist[dst[beg + i] / NPB], 1);
    __syncthreads();
    int h = hist[t];
    sc[t] = h;
    __syncthreads();
    for (int off = 1; off < 256; off <<= 1) {
        int v = (t >= off) ? sc[t - off] : 0;
        __syncthreads();
        sc[t] += v;
        __syncthreads();
    }
    int ex = sc[t] - h;            // exclusive prefix = local bucket start
    cur[t] = ex;
    loc[b * NB + t] = ex;
    cnt[b * NB + t] = h;
    __syncthreads();
    for (int i = t; i < CHUNK_A; i += 256) {
        int d = dst[beg + i];
        int k = d / NPB;
        int dl = d - k * NPB;
        int p = atomicAdd(&cur[k], 1);   // p < CHUNK_A by construction
        ebuf[p] = ((unsigned)dl << 17) | (unsigned)src[beg + i];
    }
    __syncthreads();
    for (int i = t; i < CHUNK_A; i += 256)
        gbuf[beg + i] = ebuf[i];         // fully coalesced dump
}

// stage 2: bucket totals (coalesced column sums) + exclusive scan of bases
__global__ __launch_bounds__(256) void basescan(const int* __restrict__ cnt, int* __restrict__ base,
                                                int* __restrict__ rp) {
    __shared__ int s[256];
    int t = threadIdx.x;
    int v = 0;
    for (int b = 0; b < NBLK_A; ++b) v += cnt[b * NB + t];   // coalesced across t
    s[t] = v;
    __syncthreads();
    for (int off = 1; off < 256; off <<= 1) {
        int u = (t >= off) ? s[t - off] : 0;
        __syncthreads();
        s[t] += u;
        __syncthreads();
    }
    base[t] = s[t] - v;
    if (t == 255) { base[256] = s[255]; rp[NN] = s[255]; }
}

// stage 3: per-bucket finish, thread-per-run, no LDS staging buffer.
// gbuf is sorted by (block,bucket): bucket k's data = 512 short contiguous runs.
// Phase 1 counts degrees (streaming reads); phase 3 re-reads (L2-hot) + scatters.
__global__ __launch_bounds__(512) void passB2(const unsigned* __restrict__ gbuf,
                                              const int* __restrict__ cnt, const int* __restrict__ loc,
                                              const int* __restrict__ base,
                                              int* __restrict__ rp, float* __restrict__ dinv,
                                              int* __restrict__ csr) {
    __shared__ int deg_l[NPB];
    __shared__ int off_l[NPB];
    __shared__ int s[512];
    int k = blockIdx.x, t = threadIdx.x;
    for (int i = t; i < NPB; i += 512) deg_l[i] = 0;
    __syncthreads();
    int n  = cnt[t * NB + k];              // run length (thread t = run t)
    int so = t * CHUNK_A + loc[t * NB + k];
    for (int e = 0; e < n; ++e)
        atomicAdd(&deg_l[gbuf[so + e] >> 17], 1);
    __syncthreads();
    int d0 = (t < NPB) ? deg_l[t] : 0;
    s[t] = d0;
    __syncthreads();
    for (int off = 1; off < 512; off <<= 1) {
        int v = (t >= off) ? s[t - off] : 0;
        __syncthreads();
        s[t] += v;
        __syncthreads();
    }
    if (t < NPB) off_l[t] = s[t] - d0;
    __syncthreads();
    int nodebase = k * NPB;
    int cbase = base[k];
    for (int i = t; i < NPB; i += 512) {
        int node = nodebase + i;
        if (node < NN) {
            rp[node] = cbase + off_l[i];
            dinv[node] = rsqrtf((float)deg_l[i] + 1.0f);
        }
    }
    __syncthreads();
    for (int e = 0; e < n; ++e) {
        unsigned v = gbuf[so + e];         // L2-hot (phase-1 touched)
        int p = atomicAdd(&off_l[v >> 17], 1);
        csr[cbase + p] = (int)(v & 0x1FFFFu);
    }
}

// W1 -> MFMA B-fragment layout, bf16 hi/lo: wf[ks][nt][h][lane][8]
__global__ __launch_bounds__(256) void wprep(const float* __restrict__ W1, short* __restrict__ wf) {
    int e = blockIdx.x * 256 + threadIdx.x;   // 16384 elements
    if (e >= 16384) return;
    int j = e & 7, lane = (e >> 3) & 63, nt = (e >> 9) & 3, ks = e >> 11;
    int k = ks * 32 + (lane >> 4) * 8 + j;
    int col = nt * 16 + (lane & 15);
    float w = W1[k * 64 + col];
    unsigned b = __float_as_uint(w);
    short hi = (short)(b >> 16);
    float hf = __uint_as_float(b & 0xFFFF0000u);
    float lo = w - hf;
    short lov = (short)(__float_as_uint(lo) >> 16);
    wf[((size_t)(ks * 8 + nt * 2 + 0) * 64 + lane) * 8 + j] = hi;
    wf[((size_t)(ks * 8 + nt * 2 + 1) * 64 + lane) * 8 + j] = lov;
}

// A_h[N,64] = half( dinv[i] * (x @ W1) ) via LDS-free split-bf16 MFMA.
__global__ __launch_bounds__(256) void gemm1(const float* __restrict__ x, const short* __restrict__ wf,
                                             const float* __restrict__ dinv, __half* __restrict__ Ah) {
    int wid = threadIdx.x >> 6, lane = threadIdx.x & 63;
    int g = blockIdx.x * 4 + wid;        // 16-row group per wave
    if (g >= NN / 16) return;            // 6250 groups (exact)
    int lrow = g * 16 + (lane & 15);
    int kgrp = (lane >> 4) * 8;
    const float* xp = x + (size_t)lrow * 256 + kgrp;
    f32x4 acc[4];
    #pragma unroll
    for (int nt = 0; nt < 4; ++nt) acc[nt] = (f32x4){0.f, 0.f, 0.f, 0.f};
    for (int ks = 0; ks < 8; ++ks) {
        float4 f0 = *(const float4*)(xp + ks * 32);
        float4 f1 = *(const float4*)(xp + ks * 32 + 4);
        bf16x8 a_hi, a_lo;
        const float* fp = &f0.x;
        #pragma unroll
        for (int j = 0; j < 8; ++j) {
            float f = (j < 4) ? fp[j] : (&f1.x)[j - 4];
            unsigned b = __float_as_uint(f);
            a_hi[j] = (short)(b >> 16);
            float lo = f - __uint_as_float(b & 0xFFFF0000u);
            a_lo[j] = (short)(__float_as_uint(lo) >> 16);
        }
        const short* wfk = wf + (size_t)(ks * 8) * 64 * 8;
        #pragma unroll
        for (int nt = 0; nt < 4; ++nt) {
            bf16x8 b_hi = *(const bf16x8*)(wfk + ((nt * 2 + 0) * 64 + lane) * 8);
            bf16x8 b_lo = *(const bf16x8*)(wfk + ((nt * 2 + 1) * 64 + lane) * 8);
            acc[nt] = __builtin_amdgcn_mfma_f32_16x16x32_bf16(a_hi, b_hi, acc[nt], 0, 0, 0);
            acc[nt] = __builtin_amdgcn_mfma_f32_16x16x32_bf16(a_hi, b_lo, acc[nt], 0, 0, 0);
            acc[nt] = __builtin_amdgcn_mfma_f32_16x16x32_bf16(a_lo, b_hi, acc[nt], 0, 0, 0);
        }
    }
    int mb = (lane >> 4) * 4;
    #pragma unroll
    for (int reg = 0; reg < 4; ++reg) {
        int row = g * 16 + mb + reg;
        float dv = dinv[row];
        #pragma unroll
        for (int nt = 0; nt < 4; ++nt)
            Ah[(size_t)row * 64 + nt * 16 + (lane & 15)] = __float2half(acc[nt][reg] * dv);
    }
}

// fp16 gather aggregation on 64 ch: lane = channel pair (half2), wave halves
// process 2 edges simultaneously; 16-deep unroll keeps 8 gathers in flight.
template <int P>
__global__ __launch_bounds__(256) void agg64h(const __half* __restrict__ h, __half* __restrict__ outp,
                                              const int* __restrict__ rp, const int* __restrict__ csr,
                                              const float* __restrict__ dinv) {
    int lane = threadIdx.x & 63;
    int node = (blockIdx.x << 2) + (threadIdx.x >> 6);
    if (node >= NN) return;
    int hid = lane >> 5;            // which edge of the pair
    int c2 = (lane & 31) * 2;       // channel pair base
    float dd = dinv[node];
    float ax = 0.f, ay = 0.f, bx = 0.f, by = 0.f;
    if (hid == 0) {
        __half2 sv = *(const __half2*)(h + (size_t)node * 64 + c2);
        ax = __half2float(sv.x); ay = __half2float(sv.y);
    }
    int beg = rp[node], end = rp[node + 1];
    for (int j0 = beg; j0 < end; j0 += 64) {
        int m = end - j0; if (m > 64) m = 64;
        int s = csr[j0 + (lane < m ? lane : 0)];
        int j = 0;
        for (; j + 15 < m; j += 16) {
            int i0 = __shfl(s, j + hid);
            int i1 = __shfl(s, j + 2 + hid);
            int i2 = __shfl(s, j + 4 + hid);
            int i3 = __shfl(s, j + 6 + hid);
            int i4 = __shfl(s, j + 8 + hid);
            int i5 = __shfl(s, j + 10 + hid);
            int i6 = __shfl(s, j + 12 + hid);
            int i7 = __shfl(s, j + 14 + hid);
            __half2 v0 = *(const __half2*)(h + (size_t)i0 * 64 + c2);
            __half2 v1 = *(const __half2*)(h + (size_t)i1 * 64 + c2);
            __half2 v2 = *(const __half2*)(h + (size_t)i2 * 64 + c2);
            __half2 v3 = *(const __half2*)(h + (size_t)i3 * 64 + c2);
            __half2 v4 = *(const __half2*)(h + (size_t)i4 * 64 + c2);
            __half2 v5 = *(const __half2*)(h + (size_t)i5 * 64 + c2);
            __half2 v6 = *(const __half2*)(h + (size_t)i6 * 64 + c2);
            __half2 v7 = *(const __half2*)(h + (size_t)i7 * 64 + c2);
            ax += __half2float(v0.x) + __half2float(v2.x);
            ay += __half2float(v0.y) + __half2float(v2.y);
            bx += __half2float(v1.x) + __half2float(v3.x);
            by += __half2float(v1.y) + __half2float(v3.y);
            ax += __half2float(v4.x) + __half2float(v6.x);
            ay += __half2float(v4.y) + __half2float(v6.y);
            bx += __half2float(v5.x) + __half2float(v7.x);
            by += __half2float(v5.y) + __half2float(v7.y);
        }
        for (; j + 7 < m; j += 8) {
            int i0 = __shfl(s, j + hid);
            int i1 = __shfl(s, j + 2 + hid);
            int i2 = __shfl(s, j + 4 + hid);
            int i3 = __shfl(s, j + 6 + hid);
            __half2 v0 = *(const __half2*)(h + (size_t)i0 * 64 + c2);
            __half2 v1 = *(const __half2*)(h + (size_t)i1 * 64 + c2);
            __half2 v2 = *(const __half2*)(h + (size_t)i2 * 64 + c2);
            __half2 v3 = *(const __half2*)(h + (size_t)i3 * 64 + c2);
            ax += __half2float(v0.x) + __half2float(v2.x);
            ay += __half2float(v0.y) + __half2float(v2.y);
            bx += __half2float(v1.x) + __half2float(v3.x);
            by += __half2float(v1.y) + __half2float(v3.y);
        }
        for (; j < m; j += 2) {
            int idx = j + hid;
            int cidx = idx < m ? idx : m - 1;
            int sj = __shfl(s, cidx);
            if (idx < m) {
                __half2 v = *(const __half2*)(h + (size_t)sj * 64 + c2);
                ax += __half2float(v.x); ay += __half2float(v.y);
            }
        }
    }
    float sx = ax + bx, sy = ay + by;
    sx += __shfl(sx, lane ^ 32);
    sy += __shfl(sy, lane ^ 32);
    if (hid == 0) {
        float w = (P == 2) ? dd * dd : dd;
        __half2 o;
        o.x = __float2half(sx * w); o.y = __float2half(sy * w);
        *(__half2*)(outp + (size_t)node * 64 + c2) = o;
    }
}

// fp16 gather on 32 ch, 4 edges per wave-iter, fused +b2 and log_softmax.
__global__ __launch_bounds__(256) void agg32f(const __half* __restrict__ U, float* __restrict__ outp,
                                              const int* __restrict__ rp, const int* __restrict__ csr,
                                              const float* __restrict__ dinv, const float* __restrict__ b2) {
    int lane = threadIdx.x & 63;
    int node = (blockIdx.x << 2) + (threadIdx.x >> 6);
    if (node >= NN) return;
    int gid = lane >> 4;            // which edge of the quad
    int c2 = (lane & 15) * 2;       // channel pair base
    float dd = dinv[node];
    float ax = 0.f, ay = 0.f;
    if (gid == 0) {
        __half2 sv = *(const __half2*)(U + (size_t)node * 32 + c2);
        ax = __half2float(sv.x); ay = __half2float(sv.y);
    }
    int beg = rp[node], end = rp[node + 1];
    for (int j0 = beg; j0 < end; j0 += 64) {
        int m = end - j0; if (m > 64) m = 64;
        int s = csr[j0 + (lane < m ? lane : 0)];
        int j = 0;
        for (; j + 15 < m; j += 16) {
            int i0 = __shfl(s, j + gid);
            int i1 = __shfl(s, j + 4 + gid);
            int i2 = __shfl(s, j + 8 + gid);
            int i3 = __shfl(s, j + 12 + gid);
            __half2 v0 = *(const __half2*)(U + (size_t)i0 * 32 + c2);
            __half2 v1 = *(const __half2*)(U + (size_t)i1 * 32 + c2);
            __half2 v2 = *(const __half2*)(U + (size_t)i2 * 32 + c2);
            __half2 v3 = *(const __half2*)(U + (size_t)i3 * 32 + c2);
            ax += __half2float(v0.x) + __half2float(v1.x) + __half2float(v2.x) + __half2float(v3.x);
            ay += __half2float(v0.y) + __half2float(v1.y) + __half2float(v2.y) + __half2float(v3.y);
        }
        for (; j + 7 < m; j += 8) {
            int i0 = __shfl(s, j + gid);
            int i1 = __shfl(s, j + 4 + gid);
            __half2 v0 = *(const __half2*)(U + (size_t)i0 * 32 + c2);
            __half2 v1 = *(const __half2*)(U + (size_t)i1 * 32 + c2);
            ax += __half2float(v0.x) + __half2float(v1.x);
            ay += __half2float(v0.y) + __half2float(v1.y);
        }
        for (; j < m; j += 4) {
            int idx = j + gid;
            int cidx = idx < m ? idx : m - 1;
            int sj = __shfl(s, cidx);
            if (idx < m) {
                __half2 v = *(const __half2*)(U + (size_t)sj * 32 + c2);
                ax += __half2float(v.x); ay += __half2float(v.y);
            }
        }
    }
    ax += __shfl(ax, lane ^ 16); ay += __shfl(ay, lane ^ 16);
    ax += __shfl(ax, lane ^ 32); ay += __shfl(ay, lane ^ 32);
    float v0 = ax * dd + b2[c2];
    float v1 = ay * dd + b2[c2 + 1];
    float mx = fmaxf(v0, v1);
    mx = fmaxf(mx, __shfl_xor(mx, 1));
    mx = fmaxf(mx, __shfl_xor(mx, 2));
    mx = fmaxf(mx, __shfl_xor(mx, 4));
    mx = fmaxf(mx, __shfl_xor(mx, 8));
    float sum = __expf(v0 - mx) + __expf(v1 - mx);
    sum += __shfl_xor(sum, 1);
    sum += __shfl_xor(sum, 2);
    sum += __shfl_xor(sum, 4);
    sum += __shfl_xor(sum, 8);
    if (gid == 0) {
        float ls = __logf(sum);
        *(float2*)(outp + (size_t)node * 32 + c2) = make_float2(v0 - mx - ls, v1 - mx - ls);
    }
}

__global__ __launch_bounds__(256) void bn_stats(const __half* __restrict__ A, float* __restrict__ bn) {
    int t = threadIdx.x;
    int c = t & 63, rg = t >> 6;
    float s = 0.f, sq = 0.f;
    for (int r = blockIdx.x * 4 + rg; r < NN; r += gridDim.x * 4) {
        float v = __half2float(A[(size_t)r * 64 + c]);
        s += v; sq += v * v;
    }
    __shared__ float ls[256], lq[256];
    ls[t] = s; lq[t] = sq;
    __syncthreads();
    if (t < 64) {
        float S = ls[t] + ls[t + 64] + ls[t + 128] + ls[t + 192];
        float Q = lq[t] + lq[t + 64] + lq[t + 128] + lq[t + 192];
        atomicAdd(&bn[t], S);
        atomicAdd(&bn[64 + t], Q);
    }
}

__global__ void bn_final(const float* __restrict__ bn, const float* __restrict__ gamma,
                         const float* __restrict__ beta, float* __restrict__ ss) {
    int c = threadIdx.x;   // 64 threads
    float mean = bn[c] / (float)NN;
    float var = bn[64 + c] / (float)NN - mean * mean;
    float sc = gamma[c] * rsqrtf(var + 1e-5f);
    ss[c] = sc;
    ss[64 + c] = beta[c] - mean * sc;
}

// U_h[N,32] = half( dinv[i] * (selu(bn(A[N,64])) @ W2[64,32]) )
__global__ __launch_bounds__(256) void gemm2(const __half* __restrict__ A, const float* __restrict__ W2,
                                             const float* __restrict__ ss, const float* __restrict__ dinv,
                                             __half* __restrict__ U) {
    __shared__ float w2s[64 * 32];
    __shared__ float sc[64], sh[64];
    for (int i = threadIdx.x; i < 512; i += 256)
        ((float4*)w2s)[i] = ((const float4*)W2)[i];
    if (threadIdx.x < 64) {
        sc[threadIdx.x] = ss[threadIdx.x];
        sh[threadIdx.x] = ss[64 + threadIdx.x];
    }
    __syncthreads();
    const float SELU_S = 1.0507009873554805f;
    const float SELU_AS = 1.7580993408473766f;   // scale*alpha
    int lane = threadIdx.x & 31, grp = threadIdx.x >> 5;
    int node = blockIdx.x * 8 + grp;
    if (node >= NN) return;
    const __half* Ar = A + (size_t)node * 64;
    float v0 = __half2float(Ar[lane]);
    float v1 = __half2float(Ar[lane + 32]);
    v0 = v0 * sc[lane] + sh[lane];
    v1 = v1 * sc[lane + 32] + sh[lane + 32];
    v0 = v0 > 0.f ? SELU_S * v0 : SELU_AS * (__expf(v0) - 1.0f);
    v1 = v1 > 0.f ? SELU_S * v1 : SELU_AS * (__expf(v1) - 1.0f);
    float acc = 0.f;
    #pragma unroll
    for (int j = 0; j < 32; ++j) {
        acc += __shfl(v0, j, 32) * w2s[j * 32 + lane];
        acc += __shfl(v1, j, 32) * w2s[(j + 32) * 32 + lane];
    }
    U[(size_t)node * 32 + lane] = __float2half(dinv[node] * acc);
}

extern "C" void kernel_launch(void* const* d_in, const int* in_sizes, int n_in,
                              void* d_out, int out_size, void* d_ws, size_t ws_size,
                              hipStream_t stream) {
    const float* x     = (const float*)d_in[0];
    const int*   src   = (const int*)d_in[1];
    const int*   dst   = (const int*)d_in[2];
    const float* W1    = (const float*)d_in[3];
    // d_in[4] = b1 : cancels inside BatchNorm, unused
    const float* gamma = (const float*)d_in[5];
    const float* beta  = (const float*)d_in[6];
    const float* W2    = (const float*)d_in[7];
    const float* b2    = (const float*)d_in[8];
    float* out = (float*)d_out;

    char* ws = (char*)d_ws;
    __half*   Af   = (__half*)(ws + OFF_AF);    // true h2, fp16
    unsigned* gbuf = (unsigned*)(ws + OFF_AF);  // 12.8MB overlay, consumed by passB2
    __half*   Ah   = (__half*)(ws + OFF_AH);
    __half*   Bh   = (__half*)(ws + OFF_BH);
    short*    wf   = (short*)(ws + OFF_BH);     // 64KB overlay, consumed by gemm1
    __half*   Uh   = (__half*)(ws + OFF_BH);    // 6.4MB overlay, written after Bh consumed
    int*      cnt  = (int*)(ws + OFF_CNT);      // overlays BH+64KB, consumed pre-agg
    int*      loc  = (int*)(ws + OFF_LOC);
    int*      csr  = (int*)(ws + OFF_CSR);
    int*      rp   = (int*)(ws + OFF_RP);
    float*    dinv = (float*)(ws + OFF_DINV);
    int*      base = (int*)(ws + OFF_BASE);
    float*    bn   = (float*)(ws + OFF_BN);
    float*    ssb  = (float*)(ws + OFF_SS);

    hipMemsetAsync(bn, 0, 128 * sizeof(float), stream);

    // W1 -> bf16 hi/lo MFMA fragments (parked in BH head, consumed by gemm1)
    wprep<<<64, 256, 0, stream>>>(W1, wf);

    // CSR build: LDS bucket-sort + coalesced dump, totals+scan, thread-per-run finish
    passA2<<<NBLK_A, 256, 0, stream>>>(src, dst, cnt, loc, gbuf);
    basescan<<<1, 256, 0, stream>>>(cnt, base, rp);
    passB2<<<NB, 512, 0, stream>>>(gbuf, cnt, loc, base, rp, dinv, csr);

    // conv1: Ah = half(dinv*(x@W1)) via LDS-free split-bf16 MFMA, then two fp16 propagations
    gemm1<<<(NN / 16 + 3) / 4, 256, 0, stream>>>(x, wf, dinv, Ah);
    agg64h<2><<<NN / 4, 256, 0, stream>>>(Ah, Bh, rp, csr, dinv);  // Bh pre-scaled
    agg64h<1><<<NN / 4, 256, 0, stream>>>(Bh, Af, rp, csr, dinv);  // Af = true h2 (fp16)

    // batchnorm stats (b1 cancels), fold gamma/beta into scale/shift
    bn_stats<<<1024, 256, 0, stream>>>(Af, bn);
    bn_final<<<1, 64, 0, stream>>>(bn, gamma, beta, ssb);

    // conv2: Uh = half(dinv*(selu(bn(Af)) @ W2)), then fp16 propagate + fused log_softmax
    gemm2<<<NN / 8, 256, 0, stream>>>(Af, W2, ssb, dinv, Uh);
    agg32f<<<NN / 4, 256, 0, stream>>>(Uh, out, rp, csr, dinv, b2);
}

// Round 14
// 352.520 us; speedup vs baseline: 1.1025x; 1.0057x over previous
//
#include <hip/hip_runtime.h>
#include <hip/hip_fp16.h>

#define NN 100000
#define EE 3200000
#define NB 256          // dst-range buckets
#define NPB 391         // nodes per bucket = ceil(NN/NB)
#define NBLK_A 512      // passA2 blocks (= runs per bucket)
#define CHUNK_A (EE / NBLK_A)   // 6250 edges per block

// workspace layout (bytes)
#define OFF_AF   0UL            // half[NN*64] 12.8MB true-h2  (gbuf 12.8MB overlays at start)
#define OFF_AH   25600000UL     // half[NN*64] 12.8MB h1' (gemm1 out)
#define OFF_BH   38400000UL     // half[NN*64] 12.8MB (wf 64KB + cnt/loc overlays early; Uh later)
#define OFF_CNT  (OFF_BH + 65536UL)           // int[512*256] 512KB
#define OFF_LOC  (OFF_CNT + 524288UL)         // int[512*256] 512KB
#define OFF_CSR  51200000UL     // int[EE]     12.8MB
#define OFF_RP   64000000UL     // int[NN+1]
#define OFF_DINV 64400384UL     // float[NN]
#define OFF_BASE 64808960UL     // int[257]
#define OFF_BN   64813056UL     // float[128]
#define OFF_SS   64813568UL     // float[128]
// total ~64.8 MB

typedef __attribute__((ext_vector_type(8))) short bf16x8;
typedef __attribute__((ext_vector_type(4))) float f32x4;

// ---- CSR build, stage 1: per-block LDS bucket sort + coalesced dump ----
__global__ __launch_bounds__(256) void passA2(const int* __restrict__ src, const int* __restrict__ dst,
                                              int* __restrict__ cnt, int* __restrict__ loc,
                                              unsigned* __restrict__ gbuf) {
    __shared__ unsigned ebuf[CHUNK_A];
    __shared__ int hist[NB], cur[NB], sc[NB];
    int t = threadIdx.x, b = blockIdx.x;
    hist[t] = 0;
    __syncthreads();
    int beg = b * CHUNK_A;
    for (int i = t; i < CHUNK_A; i += 256)
        atomicAdd(&hist[dst[beg + i] / NPB], 1);
    __syncthreads();
    int h = hist[t];
    sc[t] = h;
    __syncthreads();
    for (int off = 1; off < 256; off <<= 1) {
        int v = (t >= off) ? sc[t - off] : 0;
        __syncthreads();
        sc[t] += v;
        __syncthreads();
    }
    int ex = sc[t] - h;            // exclusive prefix = local bucket start
    cur[t] = ex;
    loc[b * NB + t] = ex;
    cnt[b * NB + t] = h;
    __syncthreads();
    for (int i = t; i < CHUNK_A; i += 256) {
        int d = dst[beg + i];
        int k = d / NPB;
        int dl = d - k * NPB;
        int p = atomicAdd(&cur[k], 1);   // p < CHUNK_A by construction
        ebuf[p] = ((unsigned)dl << 17) | (unsigned)src[beg + i];
    }
    __syncthreads();
    for (int i = t; i < CHUNK_A; i += 256)
        gbuf[beg + i] = ebuf[i];         // fully coalesced dump
}

// stage 2: bucket totals (coalesced column sums) + exclusive scan of bases
__global__ __launch_bounds__(256) void basescan(const int* __restrict__ cnt, int* __restrict__ base,
                                                int* __restrict__ rp) {
    __shared__ int s[256];
    int t = threadIdx.x;
    int v = 0;
    for (int b = 0; b < NBLK_A; ++b) v += cnt[b * NB + t];   // coalesced across t
    s[t] = v;
    __syncthreads();
    for (int off = 1; off < 256; off <<= 1) {
        int u = (t >= off) ? s[t - off] : 0;
        __syncthreads();
        s[t] += u;
        __syncthreads();
    }
    base[t] = s[t] - v;
    if (t == 255) { base[256] = s[255]; rp[NN] = s[255]; }
}

// stage 3: per-bucket finish, thread-per-run, no LDS staging buffer.
__global__ __launch_bounds__(512) void passB2(const unsigned* __restrict__ gbuf,
                                              const int* __restrict__ cnt, const int* __restrict__ loc,
                                              const int* __restrict__ base,
                                              int* __restrict__ rp, float* __restrict__ dinv,
                                              int* __restrict__ csr) {
    __shared__ int deg_l[NPB];
    __shared__ int off_l[NPB];
    __shared__ int s[512];
    int k = blockIdx.x, t = threadIdx.x;
    for (int i = t; i < NPB; i += 512) deg_l[i] = 0;
    __syncthreads();
    int n  = cnt[t * NB + k];              // run length (thread t = run t)
    int so = t * CHUNK_A + loc[t * NB + k];
    for (int e = 0; e < n; ++e)
        atomicAdd(&deg_l[gbuf[so + e] >> 17], 1);
    __syncthreads();
    int d0 = (t < NPB) ? deg_l[t] : 0;
    s[t] = d0;
    __syncthreads();
    for (int off = 1; off < 512; off <<= 1) {
        int v = (t >= off) ? s[t - off] : 0;
        __syncthreads();
        s[t] += v;
        __syncthreads();
    }
    if (t < NPB) off_l[t] = s[t] - d0;
    __syncthreads();
    int nodebase = k * NPB;
    int cbase = base[k];
    for (int i = t; i < NPB; i += 512) {
        int node = nodebase + i;
        if (node < NN) {
            rp[node] = cbase + off_l[i];
            dinv[node] = rsqrtf((float)deg_l[i] + 1.0f);
        }
    }
    __syncthreads();
    for (int e = 0; e < n; ++e) {
        unsigned v = gbuf[so + e];         // L2-hot (phase-1 touched)
        int p = atomicAdd(&off_l[v >> 17], 1);
        csr[cbase + p] = (int)(v & 0x1FFFFu);
    }
}

// W1 -> MFMA B-fragment layout, bf16 hi/lo: wf[ks][nt][h][lane][8]
__global__ __launch_bounds__(256) void wprep(const float* __restrict__ W1, short* __restrict__ wf) {
    int e = blockIdx.x * 256 + threadIdx.x;   // 16384 elements
    if (e >= 16384) return;
    int j = e & 7, lane = (e >> 3) & 63, nt = (e >> 9) & 3, ks = e >> 11;
    int k = ks * 32 + (lane >> 4) * 8 + j;
    int col = nt * 16 + (lane & 15);
    float w = W1[k * 64 + col];
    unsigned b = __float_as_uint(w);
    short hi = (short)(b >> 16);
    float hf = __uint_as_float(b & 0xFFFF0000u);
    float lo = w - hf;
    short lov = (short)(__float_as_uint(lo) >> 16);
    wf[((size_t)(ks * 8 + nt * 2 + 0) * 64 + lane) * 8 + j] = hi;
    wf[((size_t)(ks * 8 + nt * 2 + 1) * 64 + lane) * 8 + j] = lov;
}

// A_h[N,64] = half( dinv[i] * (x @ W1) ) via LDS-free split-bf16 MFMA.
__global__ __launch_bounds__(256) void gemm1(const float* __restrict__ x, const short* __restrict__ wf,
                                             const float* __restrict__ dinv, __half* __restrict__ Ah) {
    int wid = threadIdx.x >> 6, lane = threadIdx.x & 63;
    int g = blockIdx.x * 4 + wid;        // 16-row group per wave
    if (g >= NN / 16) return;            // 6250 groups (exact)
    int lrow = g * 16 + (lane & 15);
    int kgrp = (lane >> 4) * 8;
    const float* xp = x + (size_t)lrow * 256 + kgrp;
    f32x4 acc[4];
    #pragma unroll
    for (int nt = 0; nt < 4; ++nt) acc[nt] = (f32x4){0.f, 0.f, 0.f, 0.f};
    for (int ks = 0; ks < 8; ++ks) {
        float4 f0 = *(const float4*)(xp + ks * 32);
        float4 f1 = *(const float4*)(xp + ks * 32 + 4);
        bf16x8 a_hi, a_lo;
        const float* fp = &f0.x;
        #pragma unroll
        for (int j = 0; j < 8; ++j) {
            float f = (j < 4) ? fp[j] : (&f1.x)[j - 4];
            unsigned b = __float_as_uint(f);
            a_hi[j] = (short)(b >> 16);
            float lo = f - __uint_as_float(b & 0xFFFF0000u);
            a_lo[j] = (short)(__float_as_uint(lo) >> 16);
        }
        const short* wfk = wf + (size_t)(ks * 8) * 64 * 8;
        #pragma unroll
        for (int nt = 0; nt < 4; ++nt) {
            bf16x8 b_hi = *(const bf16x8*)(wfk + ((nt * 2 + 0) * 64 + lane) * 8);
            bf16x8 b_lo = *(const bf16x8*)(wfk + ((nt * 2 + 1) * 64 + lane) * 8);
            acc[nt] = __builtin_amdgcn_mfma_f32_16x16x32_bf16(a_hi, b_hi, acc[nt], 0, 0, 0);
            acc[nt] = __builtin_amdgcn_mfma_f32_16x16x32_bf16(a_hi, b_lo, acc[nt], 0, 0, 0);
            acc[nt] = __builtin_amdgcn_mfma_f32_16x16x32_bf16(a_lo, b_hi, acc[nt], 0, 0, 0);
        }
    }
    int mb = (lane >> 4) * 4;
    #pragma unroll
    for (int reg = 0; reg < 4; ++reg) {
        int row = g * 16 + mb + reg;
        float dv = dinv[row];
        #pragma unroll
        for (int nt = 0; nt < 4; ++nt)
            Ah[(size_t)row * 64 + nt * 16 + (lane & 15)] = __float2half(acc[nt][reg] * dv);
    }
}

// fp16 gather aggregation on 64 ch with packed-fp16 accumulation (v_pk_add_f16).
// lane = channel pair (half2); wave halves process 2 edges simultaneously.
template <int P>
__global__ __launch_bounds__(256) void agg64h(const __half* __restrict__ h, __half* __restrict__ outp,
                                              const int* __restrict__ rp, const int* __restrict__ csr,
                                              const float* __restrict__ dinv) {
    int lane = threadIdx.x & 63;
    int node = (blockIdx.x << 2) + (threadIdx.x >> 6);
    if (node >= NN) return;
    int hid = lane >> 5;            // which edge of the pair
    int c2 = (lane & 31) * 2;       // channel pair base
    float dd = dinv[node];
    float sfx = 0.f, sfy = 0.f;     // self term (fp32)
    if (hid == 0) {
        __half2 sv = *(const __half2*)(h + (size_t)node * 64 + c2);
        sfx = __half2float(sv.x); sfy = __half2float(sv.y);
    }
    __half2 haccA = __float2half2_rn(0.f);
    __half2 haccB = __float2half2_rn(0.f);
    int beg = rp[node], end = rp[node + 1];
    for (int j0 = beg; j0 < end; j0 += 64) {
        int m = end - j0; if (m > 64) m = 64;
        int s = csr[j0 + (lane < m ? lane : 0)];
        int j = 0;
        for (; j + 15 < m; j += 16) {
            int i0 = __shfl(s, j + hid);
            int i1 = __shfl(s, j + 2 + hid);
            int i2 = __shfl(s, j + 4 + hid);
            int i3 = __shfl(s, j + 6 + hid);
            int i4 = __shfl(s, j + 8 + hid);
            int i5 = __shfl(s, j + 10 + hid);
            int i6 = __shfl(s, j + 12 + hid);
            int i7 = __shfl(s, j + 14 + hid);
            __half2 v0 = *(const __half2*)(h + (size_t)i0 * 64 + c2);
            __half2 v1 = *(const __half2*)(h + (size_t)i1 * 64 + c2);
            __half2 v2 = *(const __half2*)(h + (size_t)i2 * 64 + c2);
            __half2 v3 = *(const __half2*)(h + (size_t)i3 * 64 + c2);
            __half2 v4 = *(const __half2*)(h + (size_t)i4 * 64 + c2);
            __half2 v5 = *(const __half2*)(h + (size_t)i5 * 64 + c2);
            __half2 v6 = *(const __half2*)(h + (size_t)i6 * 64 + c2);
            __half2 v7 = *(const __half2*)(h + (size_t)i7 * 64 + c2);
            __half2 tA = __hadd2(__hadd2(v0, v2), __hadd2(v4, v6));
            __half2 tB = __hadd2(__hadd2(v1, v3), __hadd2(v5, v7));
            haccA = __hadd2(haccA, tA);
            haccB = __hadd2(haccB, tB);
        }
        for (; j + 7 < m; j += 8) {
            int i0 = __shfl(s, j + hid);
            int i1 = __shfl(s, j + 2 + hid);
            int i2 = __shfl(s, j + 4 + hid);
            int i3 = __shfl(s, j + 6 + hid);
            __half2 v0 = *(const __half2*)(h + (size_t)i0 * 64 + c2);
            __half2 v1 = *(const __half2*)(h + (size_t)i1 * 64 + c2);
            __half2 v2 = *(const __half2*)(h + (size_t)i2 * 64 + c2);
            __half2 v3 = *(const __half2*)(h + (size_t)i3 * 64 + c2);
            haccA = __hadd2(haccA, __hadd2(v0, v2));
            haccB = __hadd2(haccB, __hadd2(v1, v3));
        }
        for (; j < m; j += 2) {
            int idx = j + hid;
            int cidx = idx < m ? idx : m - 1;
            int sj = __shfl(s, cidx);
            if (idx < m) {
                __half2 v = *(const __half2*)(h + (size_t)sj * 64 + c2);
                haccA = __hadd2(haccA, v);
            }
        }
    }
    float2 fA = __half22float2(haccA);
    float2 fB = __half22float2(haccB);
    float sx = sfx + fA.x + fB.x;
    float sy = sfy + fA.y + fB.y;
    sx += __shfl(sx, lane ^ 32);
    sy += __shfl(sy, lane ^ 32);
    if (hid == 0) {
        float w = (P == 2) ? dd * dd : dd;
        __half2 o;
        o.x = __float2half(sx * w); o.y = __float2half(sy * w);
        *(__half2*)(outp + (size_t)node * 64 + c2) = o;
    }
}

// fp16 gather on 32 ch, 4 edges per wave-iter, packed-fp16 accumulation,
// fused +b2 and log_softmax.
__global__ __launch_bounds__(256) void agg32f(const __half* __restrict__ U, float* __restrict__ outp,
                                              const int* __restrict__ rp, const int* __restrict__ csr,
                                              const float* __restrict__ dinv, const float* __restrict__ b2) {
    int lane = threadIdx.x & 63;
    int node = (blockIdx.x << 2) + (threadIdx.x >> 6);
    if (node >= NN) return;
    int gid = lane >> 4;            // which edge of the quad
    int c2 = (lane & 15) * 2;       // channel pair base
    float dd = dinv[node];
    float sfx = 0.f, sfy = 0.f;
    if (gid == 0) {
        __half2 sv = *(const __half2*)(U + (size_t)node * 32 + c2);
        sfx = __half2float(sv.x); sfy = __half2float(sv.y);
    }
    __half2 hacc = __float2half2_rn(0.f);
    int beg = rp[node], end = rp[node + 1];
    for (int j0 = beg; j0 < end; j0 += 64) {
        int m = end - j0; if (m > 64) m = 64;
        int s = csr[j0 + (lane < m ? lane : 0)];
        int j = 0;
        for (; j + 15 < m; j += 16) {
            int i0 = __shfl(s, j + gid);
            int i1 = __shfl(s, j + 4 + gid);
            int i2 = __shfl(s, j + 8 + gid);
            int i3 = __shfl(s, j + 12 + gid);
            __half2 v0 = *(const __half2*)(U + (size_t)i0 * 32 + c2);
            __half2 v1 = *(const __half2*)(U + (size_t)i1 * 32 + c2);
            __half2 v2 = *(const __half2*)(U + (size_t)i2 * 32 + c2);
            __half2 v3 = *(const __half2*)(U + (size_t)i3 * 32 + c2);
            hacc = __hadd2(hacc, __hadd2(__hadd2(v0, v1), __hadd2(v2, v3)));
        }
        for (; j + 7 < m; j += 8) {
            int i0 = __shfl(s, j + gid);
            int i1 = __shfl(s, j + 4 + gid);
            __half2 v0 = *(const __half2*)(U + (size_t)i0 * 32 + c2);
            __half2 v1 = *(const __half2*)(U + (size_t)i1 * 32 + c2);
            hacc = __hadd2(hacc, __hadd2(v0, v1));
        }
        for (; j < m; j += 4) {
            int idx = j + gid;
            int cidx = idx < m ? idx : m - 1;
            int sj = __shfl(s, cidx);
            if (idx < m) {
                __half2 v = *(const __half2*)(U + (size_t)sj * 32 + c2);
                hacc = __hadd2(hacc, v);
            }
        }
    }
    float2 fh = __half22float2(hacc);
    float ax = sfx + fh.x, ay = sfy + fh.y;
    ax += __shfl(ax, lane ^ 16); ay += __shfl(ay, lane ^ 16);
    ax += __shfl(ax, lane ^ 32); ay += __shfl(ay, lane ^ 32);
    float v0 = ax * dd + b2[c2];
    float v1 = ay * dd + b2[c2 + 1];
    float mx = fmaxf(v0, v1);
    mx = fmaxf(mx, __shfl_xor(mx, 1));
    mx = fmaxf(mx, __shfl_xor(mx, 2));
    mx = fmaxf(mx, __shfl_xor(mx, 4));
    mx = fmaxf(mx, __shfl_xor(mx, 8));
    float sum = __expf(v0 - mx) + __expf(v1 - mx);
    sum += __shfl_xor(sum, 1);
    sum += __shfl_xor(sum, 2);
    sum += __shfl_xor(sum, 4);
    sum += __shfl_xor(sum, 8);
    if (gid == 0) {
        float ls = __logf(sum);
        *(float2*)(outp + (size_t)node * 32 + c2) = make_float2(v0 - mx - ls, v1 - mx - ls);
    }
}

__global__ __launch_bounds__(256) void bn_stats(const __half* __restrict__ A, float* __restrict__ bn) {
    int t = threadIdx.x;
    int c = t & 63, rg = t >> 6;
    float s = 0.f, sq = 0.f;
    for (int r = blockIdx.x * 4 + rg; r < NN; r += gridDim.x * 4) {
        float v = __half2float(A[(size_t)r * 64 + c]);
        s += v; sq += v * v;
    }
    __shared__ float ls[256], lq[256];
    ls[t] = s; lq[t] = sq;
    __syncthreads();
    if (t < 64) {
        float S = ls[t] + ls[t + 64] + ls[t + 128] + ls[t + 192];
        float Q = lq[t] + lq[t + 64] + lq[t + 128] + lq[t + 192];
        atomicAdd(&bn[t], S);
        atomicAdd(&bn[64 + t], Q);
    }
}

__global__ void bn_final(const float* __restrict__ bn, const float* __restrict__ gamma,
                         const float* __restrict__ beta, float* __restrict__ ss) {
    int c = threadIdx.x;   // 64 threads
    float mean = bn[c] / (float)NN;
    float var = bn[64 + c] / (float)NN - mean * mean;
    float sc = gamma[c] * rsqrtf(var + 1e-5f);
    ss[c] = sc;
    ss[64 + c] = beta[c] - mean * sc;
}

// U_h[N,32] = half( dinv[i] * (selu(bn(A[N,64])) @ W2[64,32]) )
__global__ __launch_bounds__(256) void gemm2(const __half* __restrict__ A, const float* __restrict__ W2,
                                             const float* __restrict__ ss, const float* __restrict__ dinv,
                                             __half* __restrict__ U) {
    __shared__ float w2s[64 * 32];
    __shared__ float sc[64], sh[64];
    for (int i = threadIdx.x; i < 512; i += 256)
        ((float4*)w2s)[i] = ((const float4*)W2)[i];
    if (threadIdx.x < 64) {
        sc[threadIdx.x] = ss[threadIdx.x];
        sh[threadIdx.x] = ss[64 + threadIdx.x];
    }
    __syncthreads();
    const float SELU_S = 1.0507009873554805f;
    const float SELU_AS = 1.7580993408473766f;   // scale*alpha
    int lane = threadIdx.x & 31, grp = threadIdx.x >> 5;
    int node = blockIdx.x * 8 + grp;
    if (node >= NN) return;
    const __half* Ar = A + (size_t)node * 64;
    float v0 = __half2float(Ar[lane]);
    float v1 = __half2float(Ar[lane + 32]);
    v0 = v0 * sc[lane] + sh[lane];
    v1 = v1 * sc[lane + 32] + sh[lane + 32];
    v0 = v0 > 0.f ? SELU_S * v0 : SELU_AS * (__expf(v0) - 1.0f);
    v1 = v1 > 0.f ? SELU_S * v1 : SELU_AS * (__expf(v1) - 1.0f);
    float acc = 0.f;
    #pragma unroll
    for (int j = 0; j < 32; ++j) {
        acc += __shfl(v0, j, 32) * w2s[j * 32 + lane];
        acc += __shfl(v1, j, 32) * w2s[(j + 32) * 32 + lane];
    }
    U[(size_t)node * 32 + lane] = __float2half(dinv[node] * acc);
}

extern "C" void kernel_launch(void* const* d_in, const int* in_sizes, int n_in,
                              void* d_out, int out_size, void* d_ws, size_t ws_size,
                              hipStream_t stream) {
    const float* x     = (const float*)d_in[0];
    const int*   src   = (const int*)d_in[1];
    const int*   dst   = (const int*)d_in[2];
    const float* W1    = (const float*)d_in[3];
    // d_in[4] = b1 : cancels inside BatchNorm, unused
    const float* gamma = (const float*)d_in[5];
    const float* beta  = (const float*)d_in[6];
    const float* W2    = (const float*)d_in[7];
    const float* b2    = (const float*)d_in[8];
    float* out = (float*)d_out;

    char* ws = (char*)d_ws;
    __half*   Af   = (__half*)(ws + OFF_AF);    // true h2, fp16
    unsigned* gbuf = (unsigned*)(ws + OFF_AF);  // 12.8MB overlay, consumed by passB2
    __half*   Ah   = (__half*)(ws + OFF_AH);
    __half*   Bh   = (__half*)(ws + OFF_BH);
    short*    wf   = (short*)(ws + OFF_BH);     // 64KB overlay, consumed by gemm1
    __half*   Uh   = (__half*)(ws + OFF_BH);    // 6.4MB overlay, written after Bh consumed
    int*      cnt  = (int*)(ws + OFF_CNT);      // overlays BH+64KB, consumed pre-agg
    int*      loc  = (int*)(ws + OFF_LOC);
    int*      csr  = (int*)(ws + OFF_CSR);
    int*      rp   = (int*)(ws + OFF_RP);
    float*    dinv = (float*)(ws + OFF_DINV);
    int*      base = (int*)(ws + OFF_BASE);
    float*    bn   = (float*)(ws + OFF_BN);
    float*    ssb  = (float*)(ws + OFF_SS);

    hipMemsetAsync(bn, 0, 128 * sizeof(float), stream);

    // W1 -> bf16 hi/lo MFMA fragments (parked in BH head, consumed by gemm1)
    wprep<<<64, 256, 0, stream>>>(W1, wf);

    // CSR build: LDS bucket-sort + coalesced dump, totals+scan, thread-per-run finish
    passA2<<<NBLK_A, 256, 0, stream>>>(src, dst, cnt, loc, gbuf);
    basescan<<<1, 256, 0, stream>>>(cnt, base, rp);
    passB2<<<NB, 512, 0, stream>>>(gbuf, cnt, loc, base, rp, dinv, csr);

    // conv1: Ah = half(dinv*(x@W1)) via LDS-free split-bf16 MFMA, then two fp16 propagations
    gemm1<<<(NN / 16 + 3) / 4, 256, 0, stream>>>(x, wf, dinv, Ah);
    agg64h<2><<<NN / 4, 256, 0, stream>>>(Ah, Bh, rp, csr, dinv);  // Bh pre-scaled
    agg64h<1><<<NN / 4, 256, 0, stream>>>(Bh, Af, rp, csr, dinv);  // Af = true h2 (fp16)

    // batchnorm stats (b1 cancels), fold gamma/beta into scale/shift
    bn_stats<<<1024, 256, 0, stream>>>(Af, bn);
    bn_final<<<1, 64, 0, stream>>>(bn, gamma, beta, ssb);

    // conv2: Uh = half(dinv*(selu(bn(Af)) @ W2)), then fp16 propagate + fused log_softmax
    gemm2<<<NN / 8, 256, 0, stream>>>(Af, W2, ssb, dinv, Uh);
    agg32f<<<NN / 4, 256, 0, stream>>>(Uh, out, rp, csr, dinv, b2);
}